// Round 9
// baseline (1316.209 us; speedup 1.0000x reference)
//
#include <hip/hip_runtime.h>
#include <math.h>

typedef _Float16 f16;
typedef _Float16 f16x4 __attribute__((ext_vector_type(4)));
typedef _Float16 f16x8 __attribute__((ext_vector_type(8)));
typedef float f32x4 __attribute__((ext_vector_type(4)));
typedef float fvec4 __attribute__((ext_vector_type(4)));

#define EP_SILU 0
#define EP_LIN  1
#define EP_ZUP  2
#define EP_OUT  3
#define EP_ADDP 4

// Transpose-role descriptor: nMat matrices W (R,C) fp32 row-major ->
// WT (C,R) f16 row-major, strides in ELEMENTS.
struct TDesc {
  const float* W;
  f16* WT;
  long long sW, sWT;
  int R, C, nMat;
};

// ---------------------------------------------------------------------------
// async global -> LDS, 16B per lane. LDS dest is wave-uniform base + lane*16.
// ---------------------------------------------------------------------------
__device__ __forceinline__ void gll16(const void* g, void* l) {
  __builtin_amdgcn_global_load_lds((__attribute__((address_space(1))) void*)g,
                                   (__attribute__((address_space(3))) void*)l,
                                   16, 0, 0);
}

// 256-thread stage of a 128x32 f16 tile (row stride ld) -> LDS linear [128][32]
// (fallback gemm_bt only; no swizzle)
__device__ __forceinline__ void stage_tile(const f16* __restrict__ g, int ld,
                                           f16* ldsTile, int tid, int wid) {
#pragma unroll
  for (int p = 0; p < 2; ++p) {
    int row = p * 64 + (tid >> 2);
    int col = (tid & 3) * 8;
    gll16(g + (size_t)row * ld + col, ldsTile + p * 2048 + wid * 512);
  }
}

// ---------------------------------------------------------------------------
// One 64x64 transpose+convert tile via LDS. 256 threads.
// ---------------------------------------------------------------------------
__device__ __forceinline__ void tpose_tile(const float* __restrict__ W,
                                           f16* __restrict__ WT, int R, int C,
                                           int r0, int c0, f16 (*t)[72],
                                           int tid) {
#pragma unroll
  for (int p = 0; p < 4; ++p) {
    int lin = p * 1024 + tid * 4;
    int r = lin >> 6, c4 = lin & 63;
    fvec4 v = *(const fvec4*)(W + (size_t)(r0 + r) * C + c0 + c4);
    t[c4 + 0][r] = (f16)v[0];
    t[c4 + 1][r] = (f16)v[1];
    t[c4 + 2][r] = (f16)v[2];
    t[c4 + 3][r] = (f16)v[3];
  }
  __syncthreads();
#pragma unroll
  for (int p = 0; p < 4; ++p) {
    int lin = p * 1024 + tid * 4;
    int c = lin >> 6, r4 = lin & 63;
    f16x4 h;
    h[0] = t[c][r4 + 0];
    h[1] = t[c][r4 + 1];
    h[2] = t[c][r4 + 2];
    h[3] = t[c][r4 + 3];
    *(f16x4*)(WT + (size_t)(c0 + c) * R + r0 + r4) = h;
  }
  __syncthreads();
}

__device__ void run_role(const TDesc d, int rid, int nr, f16 (*t)[72],
                         int tid) {
  if (d.nMat <= 0 || d.W == nullptr) return;
  int tR = d.R >> 6, tC = d.C >> 6;
  int tpm = tR * tC, tot = tpm * d.nMat;
  for (int i = rid; i < tot; i += nr) {
    int m = i / tpm, rem = i - m * tpm;
    int r0 = (rem % tR) << 6, c0 = (rem / tR) << 6;
    tpose_tile(d.W + (size_t)m * d.sW, d.WT + (size_t)m * d.sWT, d.R, d.C, r0,
               c0, t, tid);
  }
}

// ---------------------------------------------------------------------------
// gemm4: 4-wave 64x128-tile GEMM, m97-style double-buffered K-loop (K-step 32,
// 24 KB LDS -> multiple blocks/CU), k-quad XOR swizzle on LDS (both sides:
// linear LDS dest + inverse-swizzled global SOURCE on stage, swizzled READ).
//   C(M,N) = A(M,K) * BT(N,K)^T, f16 operands, fp32 accum.
// Waves: wr=wid>>1 (2 row-halves of 32), wc=wid&1 (2 col-halves of 64);
// per wave 2x4 fragments of 16x16x32 MFMA.
// Blocks >= nbGemm run transpose roles (z==0 only). Batched over grid.z.
// ---------------------------------------------------------------------------
template <int EP>
__global__ void __launch_bounds__(256)
gemm4(const f16* __restrict__ A, int lda, const f16* __restrict__ BT, int ldb,
      long long sBT, int K, int N, int gx, int nbGemm,
      const float* __restrict__ bias, long long sBias,
      const f16* __restrict__ addP, f16* __restrict__ outH,
      float* __restrict__ outF, long long sOut, const f16* __restrict__ zOld,
      const float* __restrict__ noise, float aT, float nsT, TDesc dA,
      TDesc dB) {
  __shared__ __align__(16) char smem[24576];  // 2 slots x (A 4KB + B 8KB)
  const int tid = threadIdx.x;
  const int bid = blockIdx.x;

  if (bid >= nbGemm) {  // transpose-role block
    if (blockIdx.z == 0) {
      int rid = bid - nbGemm, nr = (int)gridDim.x - nbGemm;
      f16(*t)[72] = reinterpret_cast<f16(*)[72]>(smem);
      run_role(dA, rid, nr, t, tid);
      run_role(dB, rid, nr, t, tid);
    }
    return;
  }

  const int z = blockIdx.z;
  const f16* BTz = BT + (size_t)z * sBT;
  f16* outHz = outH ? outH + (size_t)z * sOut : nullptr;
  float* outFz = outF ? outF + (size_t)z * sOut : nullptr;

  // bijective XCD swizzle (nbGemm % 8 == 0)
  const int cpx = nbGemm >> 3;
  const int swz = (bid & 7) * cpx + (bid >> 3);
  const int by = swz / gx, bx = swz % gx;
  const int m0 = by * 64, n0 = bx * 128;

  const int lane = tid & 63, wid = tid >> 6;
  const int wr = wid >> 1, wc = wid & 1;
  const int lr = lane & 15, kg = lane >> 4;
  const int xq = (lr >> 1) & 3;  // read-side swizzle: (row>>1)&3 == (lr>>1)&3

  f16* lds = (f16*)smem;  // slot s at s*6144: A [64][32] then B [128][32]
  f32x4 acc[2][4] = {};

  const int nk = K >> 5;
  auto stageAB = [&](int kt, int buf) {
    int k0 = kt << 5;
    f16* sA = lds + buf * 6144;
    f16* sB = sA + 2048;
    {  // A: 64x32 = 256 lanes x 16B; source quad inverse-swizzled
      int row = tid >> 2;
      int q = (tid & 3) ^ ((tid >> 3) & 3);
      gll16(A + (size_t)(m0 + row) * lda + k0 + q * 8, sA + tid * 8);
    }
#pragma unroll
    for (int p = 0; p < 2; ++p) {  // B: 128x32 = 512 lanes x 16B
      int pos = p * 256 + tid;
      int row = pos >> 2;
      int q = (pos & 3) ^ ((pos >> 3) & 3);
      gll16(BTz + (size_t)(n0 + row) * ldb + k0 + q * 8, sB + pos * 8);
    }
  };

  stageAB(0, 0);
  __syncthreads();
  int cur = 0;
  for (int kt = 0; kt < nk; ++kt) {
    if (kt + 1 < nk) stageAB(kt + 1, cur ^ 1);
    const f16* LA = lds + cur * 6144;
    const f16* LB = LA + 2048;
    f16x8 a[2], b[4];
#pragma unroll
    for (int m = 0; m < 2; ++m) {
      int row = wr * 32 + m * 16 + lr;
      a[m] = *(const f16x8*)(LA + row * 32 + (kg ^ xq) * 8);
    }
#pragma unroll
    for (int n = 0; n < 4; ++n) {
      int row = wc * 64 + n * 16 + lr;
      b[n] = *(const f16x8*)(LB + row * 32 + (kg ^ xq) * 8);
    }
#pragma unroll
    for (int m = 0; m < 2; ++m)
#pragma unroll
      for (int n = 0; n < 4; ++n)
        acc[m][n] = __builtin_amdgcn_mfma_f32_16x16x32_f16(a[m], b[n],
                                                           acc[m][n], 0, 0, 0);
    __syncthreads();
    cur ^= 1;
  }

  // Epilogue. C/D layout: col = lane&15, row = (lane>>4)*4 + r (m89).
  float bcol[4];
  if constexpr (EP != EP_ADDP) {
    const float* biasz = bias + (size_t)z * sBias;
#pragma unroll
    for (int n = 0; n < 4; ++n) bcol[n] = biasz[n0 + wc * 64 + n * 16 + lr];
  }

#pragma unroll
  for (int m = 0; m < 2; ++m) {
    int rowb = m0 + wr * 32 + m * 16 + kg * 4;
#pragma unroll
    for (int n = 0; n < 4; ++n) {
      int col = n0 + wc * 64 + n * 16 + lr;
#pragma unroll
      for (int r = 0; r < 4; ++r) {
        size_t idx = (size_t)(rowb + r) * N + col;
        float v = acc[m][n][r];
        if constexpr (EP == EP_ADDP) v += (float)addP[idx];
        else v += bcol[n];
        if constexpr (EP == EP_SILU || EP == EP_ADDP) {
          v = v / (1.0f + __expf(-v));
          outHz[idx] = (f16)v;
        } else if constexpr (EP == EP_LIN) {
          outHz[idx] = (f16)v;
        } else if constexpr (EP == EP_OUT) {
          outFz[idx] = v;
        } else {  // EP_ZUP: z' = a*(acc+b) + (1-a)*z_old + ns*noise (f16 chain)
          float zn = aT * v + (1.0f - aT) * (float)zOld[idx] + nsT * noise[idx];
          outHz[idx] = (f16)zn;
        }
      }
    }
  }
}

// ---------------------------------------------------------------------------
// 4-wave 128x128 GEMM (round-1 structure) — fallback path only.
// ---------------------------------------------------------------------------
template <int EP>
__global__ void __launch_bounds__(256)
gemm_bt(const f16* __restrict__ A0, const f16* __restrict__ A1, int Ksplit,
        int lda, const f16* __restrict__ BT, int ldb, long long sBT, int K,
        int N, int gx, const float* __restrict__ bias, long long sBias,
        f16* __restrict__ outH, float* __restrict__ outF, long long sOut,
        const float* __restrict__ zOld, const float* __restrict__ noise,
        float aT, float nsT) {
  __shared__ __align__(16) f16 lds[2][2][128 * 32];
  const int tid = threadIdx.x;
  const int z = blockIdx.z;
  const f16* BTz = BT + (size_t)z * sBT;
  f16* outHz = outH ? outH + (size_t)z * sOut : nullptr;
  float* outFz = outF ? outF + (size_t)z * sOut : nullptr;

  const int lane = tid & 63, wid = tid >> 6;
  const int wr = wid >> 1, wc = wid & 1;
  const int lr = lane & 15, kg = lane >> 4;
  const int by = blockIdx.x / gx, bx = blockIdx.x - by * gx;
  const int m0 = by * 128, n0 = bx * 128;

  f32x4 acc[4][4] = {};
  const int nk = K >> 5;
  auto stageAB = [&](int kt, int buf) {
    int k0 = kt << 5;
    const f16* Abase = (k0 < Ksplit)
                           ? (A0 + (size_t)m0 * lda + k0)
                           : (A1 + (size_t)m0 * lda + (k0 - Ksplit));
    stage_tile(Abase, lda, &lds[buf][0][0], tid, wid);
    stage_tile(BTz + (size_t)n0 * ldb + k0, ldb, &lds[buf][1][0], tid, wid);
  };

  stageAB(0, 0);
  __syncthreads();
  int cur = 0;
  for (int kt = 0; kt < nk; ++kt) {
    if (kt + 1 < nk) stageAB(kt + 1, cur ^ 1);
    const f16* LA = &lds[cur][0][0];
    const f16* LB = &lds[cur][1][0];
    f16x8 a[4], b[4];
#pragma unroll
    for (int m = 0; m < 4; ++m)
      a[m] = *(const f16x8*)(LA + ((wr * 64 + m * 16 + lr) * 32 + kg * 8));
#pragma unroll
    for (int n = 0; n < 4; ++n)
      b[n] = *(const f16x8*)(LB + ((wc * 64 + n * 16 + lr) * 32 + kg * 8));
#pragma unroll
    for (int m = 0; m < 4; ++m)
#pragma unroll
      for (int n = 0; n < 4; ++n)
        acc[m][n] = __builtin_amdgcn_mfma_f32_16x16x32_f16(a[m], b[n],
                                                           acc[m][n], 0, 0, 0);
    __syncthreads();
    cur ^= 1;
  }

  float bcol[4];
  const float* biasz = bias + (size_t)z * sBias;
#pragma unroll
  for (int n = 0; n < 4; ++n) bcol[n] = biasz[n0 + wc * 64 + n * 16 + lr];

#pragma unroll
  for (int m = 0; m < 4; ++m) {
    int rowb = m0 + wr * 64 + m * 16 + kg * 4;
#pragma unroll
    for (int n = 0; n < 4; ++n) {
      int col = n0 + wc * 64 + n * 16 + lr;
#pragma unroll
      for (int r = 0; r < 4; ++r) {
        size_t idx = (size_t)(rowb + r) * N + col;
        float v = acc[m][n][r] + bcol[n];
        if constexpr (EP == EP_SILU) {
          v = v / (1.0f + __expf(-v));
          outHz[idx] = (f16)v;
        } else if constexpr (EP == EP_LIN) {
          outHz[idx] = (f16)v;
        } else if constexpr (EP == EP_OUT) {
          outFz[idx] = v;
        } else {
          float zn = aT * v + (1.0f - aT) * zOld[idx] + nsT * noise[idx];
          outFz[idx] = zn;
          outHz[idx] = (f16)zn;
        }
      }
    }
  }
}

// ---------------------------------------------------------------------------
__global__ void __launch_bounds__(256) tconv_role(TDesc d) {
  __shared__ __align__(16) f16 t[64][72];
  run_role(d, blockIdx.x, gridDim.x, t, threadIdx.x);
}

__global__ void __launch_bounds__(256)
cvt4(const float* __restrict__ in, f16* __restrict__ outp, int n4) {
  int i = blockIdx.x * 256 + threadIdx.x;
  if (i >= n4) return;
  fvec4 v = *(const fvec4*)(in + (size_t)i * 4);
  f16x4 h;
  h[0] = (f16)v[0];
  h[1] = (f16)v[1];
  h[2] = (f16)v[2];
  h[3] = (f16)v[3];
  *(f16x4*)(outp + (size_t)i * 4) = h;
}

__global__ void __launch_bounds__(256)
zinit4(const float* __restrict__ z0, float* __restrict__ z32,
       f16* __restrict__ z16, int n4) {
  int i = blockIdx.x * 256 + threadIdx.x;
  if (i >= n4) return;
  fvec4 v = *(const fvec4*)(z0 + (size_t)i * 4);
  *(fvec4*)(z32 + (size_t)i * 4) = v;
  f16x4 h;
  h[0] = (f16)v[0];
  h[1] = (f16)v[1];
  h[2] = (f16)v[2];
  h[3] = (f16)v[3];
  *(f16x4*)(z16 + (size_t)i * 4) = h;
}

// ---------------------------------------------------------------------------
extern "C" void kernel_launch(void* const* d_in, const int* in_sizes, int n_in,
                              void* d_out, int out_size, void* d_ws,
                              size_t ws_size, hipStream_t stream) {
  const int B = 2048, IN = 1024, H = 2048, OUT = 1024, T = 10;
  const float* x = (const float*)d_in[0];
  const float* z0 = (const float*)d_in[1];
  const float* noise = (const float*)d_in[2];
  const float* w1 = (const float*)d_in[3];
  const float* b1 = (const float*)d_in[4];
  const float* w2 = (const float*)d_in[5];
  const float* b2 = (const float*)d_in[6];
  const float* wA = (const float*)d_in[7];
  const float* bA = (const float*)d_in[8];
  const float* wB = (const float*)d_in[9];
  const float* bB = (const float*)d_in[10];
  const float* wC = (const float*)d_in[11];
  const float* bC = (const float*)d_in[12];
  float* out = (float*)d_out;

  char* ws = (char*)d_ws;
  size_t off = 0;
  auto alloc = [&](size_t bytes) {
    void* p = ws + off;
    off += (bytes + 255) & ~(size_t)255;
    return p;
  };
  TDesc none = {nullptr, nullptr, 0, 0, 0, 0, 0};

  const size_t FAST_NEED = 273000000ull;
  if (ws_size >= FAST_NEED) {
    // ---------------- fast path ------------------------------------------
    f16* x16 = (f16*)alloc((size_t)B * IN * 2);
    f16* h16 = (f16*)alloc((size_t)B * H * 2);
    f16* xe16 = (f16*)alloc((size_t)B * H * 2);
    f16* z16 = (f16*)alloc((size_t)B * H * 2);
    f16* u16 = (f16*)alloc((size_t)B * H * 2);
    f16* p16 = (f16*)alloc((size_t)T * B * H * 2);
    f16* w1T = (f16*)alloc((size_t)IN * H * 2);
    f16* w2T = (f16*)alloc((size_t)H * H * 2);
    f16* wCT = (f16*)alloc((size_t)H * OUT * 2);
    f16* wAbotT = (f16*)alloc((size_t)T * H * H * 2);
    f16* wAtopT[2] = {(f16*)alloc((size_t)H * H * 2),
                      (f16*)alloc((size_t)H * H * 2)};
    f16* wBT2[2] = {(f16*)alloc((size_t)H * H * 2),
                    (f16*)alloc((size_t)H * H * 2)};

    cvt4<<<B * IN / 4 / 256, 256, 0, stream>>>(x, x16, B * IN / 4);
    cvt4<<<B * H / 4 / 256, 256, 0, stream>>>(z0, z16, B * H / 4);
    tconv_role<<<512, 256, 0, stream>>>(TDesc{w1, w1T, 0, 0, IN, H, 1});

    // embed1: h = silu(x @ w1 + b1); roles: w2T, wAbot 0..3
    gemm4<EP_SILU><<<640, 256, 0, stream>>>(
        x16, IN, w1T, IN, 0, IN, H, 16, 512, b1, 0, nullptr, h16, nullptr, 0,
        nullptr, nullptr, 0.f, 0.f, TDesc{w2, w2T, 0, 0, H, H, 1},
        TDesc{wA + (size_t)H * H, wAbotT, (long long)2 * H * H,
              (long long)H * H, H, H, 4});
    // embed2: xe = h @ w2 + b2; roles: wCT, wAbot 4..9
    gemm4<EP_LIN><<<640, 256, 0, stream>>>(
        h16, H, w2T, H, 0, H, H, 16, 512, b2, 0, nullptr, xe16, nullptr, 0,
        nullptr, nullptr, 0.f, 0.f, TDesc{wC, wCT, 0, 0, H, OUT, 1},
        TDesc{wA + (size_t)H * H + (size_t)4 * 2 * H * H,
              wAbotT + (size_t)4 * H * H, (long long)2 * H * H,
              (long long)H * H, H, H, 6});
    tconv_role<<<256, 256, 0, stream>>>(TDesc{wA, wAtopT[0], 0, 0, H, H, 1});

    // P_t = xe @ wAbot_t + bA_t, all t batched (grid.z = t)
    gemm4<EP_LIN><<<dim3(512, 1, T), 256, 0, stream>>>(
        xe16, H, wAbotT, H, (long long)H * H, H, H, 16, 512, bA, H, nullptr,
        p16, nullptr, (long long)B * H, nullptr, nullptr, 0.f, 0.f, none,
        none);

    for (int t = 0; t < T; ++t) {
      float alpha = (float)(0.99 - 0.01 * (double)t);
      float ns = sqrtf(1.0f - alpha);
      // u = silu(z @ wAtop_t + P_t); role: transpose wB_t
      gemm4<EP_ADDP><<<576, 256, 0, stream>>>(
          z16, H, wAtopT[t & 1], H, 0, H, H, 16, 512, nullptr, 0,
          p16 + (size_t)t * B * H, u16, nullptr, 0, nullptr, nullptr, 0.f,
          0.f, TDesc{wB + (size_t)t * H * H, wBT2[t & 1], 0, 0, H, H, 1},
          none);
      // z = a*(u @ wB_t + bB_t) + (1-a)z + ns*n_t; role: wAtop_{t+1}
      TDesc nextA = (t < T - 1)
                        ? TDesc{wA + (size_t)(t + 1) * 2 * H * H,
                                wAtopT[(t + 1) & 1], 0, 0, H, H, 1}
                        : none;
      gemm4<EP_ZUP><<<576, 256, 0, stream>>>(
          u16, H, wBT2[t & 1], H, 0, H, H, 16, 512, bB + (size_t)t * H, 0,
          nullptr, z16, nullptr, 0, z16, noise + (size_t)t * B * H, alpha, ns,
          nextA, none);
    }
    // out = z @ wC + bC  (M=2048 -> gy=32, N=1024 -> gx=8, 256 blocks)
    gemm4<EP_OUT><<<256, 256, 0, stream>>>(
        z16, H, wCT, H, 0, H, OUT, 8, 256, bC, 0, nullptr, nullptr, out, 0,
        nullptr, nullptr, 0.f, 0.f, none, none);
  } else {
    // ---------------- fallback: round-1 flow ------------------------------
    f16* x16 = (f16*)alloc((size_t)B * IN * 2);
    f16* h16 = (f16*)alloc((size_t)B * H * 2);
    f16* xe16 = (f16*)alloc((size_t)B * H * 2);
    f16* z16 = (f16*)alloc((size_t)B * H * 2);
    f16* u16 = (f16*)alloc((size_t)B * H * 2);
    float* z32 = (float*)alloc((size_t)B * H * 4);
    f16* w1T = (f16*)alloc((size_t)IN * H * 2);
    f16* w2T = (f16*)alloc((size_t)H * H * 2);
    f16* wCT = (f16*)alloc((size_t)H * OUT * 2);
    f16* wAT = (f16*)alloc((size_t)2 * H * H * 2);
    f16* wBT = (f16*)alloc((size_t)H * H * 2);

    cvt4<<<B * IN / 4 / 256, 256, 0, stream>>>(x, x16, B * IN / 4);
    zinit4<<<B * H / 4 / 256, 256, 0, stream>>>(z0, z32, z16, B * H / 4);
    tconv_role<<<512, 256, 0, stream>>>(TDesc{w1, w1T, 0, 0, IN, H, 1});
    tconv_role<<<1024, 256, 0, stream>>>(TDesc{w2, w2T, 0, 0, H, H, 1});
    tconv_role<<<512, 256, 0, stream>>>(TDesc{wC, wCT, 0, 0, H, OUT, 1});

    gemm_bt<EP_SILU><<<dim3(256, 1, 1), 256, 0, stream>>>(
        x16, x16, IN, IN, w1T, IN, 0, IN, H, 16, b1, 0, h16, nullptr, 0,
        nullptr, nullptr, 0.f, 0.f);
    gemm_bt<EP_LIN><<<dim3(256, 1, 1), 256, 0, stream>>>(
        h16, h16, H, H, w2T, H, 0, H, H, 16, b2, 0, xe16, nullptr, 0, nullptr,
        nullptr, 0.f, 0.f);

    for (int t = 0; t < T; ++t) {
      float alpha = (float)(0.99 - 0.01 * (double)t);
      float ns = sqrtf(1.0f - alpha);
      tconv_role<<<1024, 256, 0, stream>>>(
          TDesc{wA + (size_t)t * 2 * H * H, wAT, 0, 0, 2 * H, H, 1});
      gemm_bt<EP_SILU><<<dim3(256, 1, 1), 256, 0, stream>>>(
          z16, xe16, H, H, wAT, 2 * H, 0, 2 * H, H, 16, bA + (size_t)t * H, 0,
          u16, nullptr, 0, nullptr, nullptr, 0.f, 0.f);
      tconv_role<<<1024, 256, 0, stream>>>(
          TDesc{wB + (size_t)t * H * H, wBT, 0, 0, H, H, 1});
      gemm_bt<EP_ZUP><<<dim3(256, 1, 1), 256, 0, stream>>>(
          u16, u16, H, H, wBT, H, 0, H, H, 16, bB + (size_t)t * H, 0, z16,
          z32, 0, z32, noise + (size_t)t * B * H, alpha, ns);
    }
    gemm_bt<EP_OUT><<<dim3(128, 1, 1), 256, 0, stream>>>(
        z16, z16, H, H, wCT, H, 0, H, OUT, 8, bC, 0, nullptr, out, 0, nullptr,
        nullptr, 0.f, 0.f);
  }
}

// Round 10
// 1108.386 us; speedup vs baseline: 1.1875x; 1.1875x over previous
//
#include <hip/hip_runtime.h>
#include <math.h>

typedef _Float16 f16;
typedef _Float16 f16x4 __attribute__((ext_vector_type(4)));
typedef _Float16 f16x8 __attribute__((ext_vector_type(8)));
typedef float f32x4 __attribute__((ext_vector_type(4)));
typedef float fvec4 __attribute__((ext_vector_type(4)));

#define EP_SILU 0
#define EP_LIN  1
#define EP_ZUP  2
#define EP_OUT  3
#define EP_ADDP 4

// Transpose-role descriptor: nMat matrices W (R,C) fp32 row-major ->
// WT (C,R) f16 row-major, strides in ELEMENTS.
struct TDesc {
  const float* W;
  f16* WT;
  long long sW, sWT;
  int R, C, nMat;
};

// ---------------------------------------------------------------------------
// async global -> LDS, 16B per lane. LDS dest is wave-uniform base + lane*16.
// ---------------------------------------------------------------------------
__device__ __forceinline__ void gll16(const void* g, void* l) {
  __builtin_amdgcn_global_load_lds((__attribute__((address_space(1))) void*)g,
                                   (__attribute__((address_space(3))) void*)l,
                                   16, 0, 0);
}

// 256-thread stage of a 128x32 f16 tile (row stride ld) -> LDS linear [128][32]
// (fallback gemm_bt only; no swizzle)
__device__ __forceinline__ void stage_tile(const f16* __restrict__ g, int ld,
                                           f16* ldsTile, int tid, int wid) {
#pragma unroll
  for (int p = 0; p < 2; ++p) {
    int row = p * 64 + (tid >> 2);
    int col = (tid & 3) * 8;
    gll16(g + (size_t)row * ld + col, ldsTile + p * 2048 + wid * 512);
  }
}

// 512-thread stage of a 128x32 f16 tile -> LDS linear [128][32], k-quad XOR
// swizzled (both-sides, rule #21): LDS dest linear, global source col-quad
// inverse-swizzled by row bits 1-2; reads use (kg ^ xq). Verified round 9:
// SQ_LDS_BANK_CONFLICT -> 0.
__device__ __forceinline__ void stage8s(const f16* __restrict__ g, int ld,
                                        f16* ldsTile, int tid) {
  int row = tid >> 2;
  int q = (tid & 3) ^ ((tid >> 3) & 3);
  gll16(g + (size_t)row * ld + q * 8, ldsTile + tid * 8);
}

// ---------------------------------------------------------------------------
// One 64x64 transpose+convert tile via LDS. 512 threads.
// ---------------------------------------------------------------------------
__device__ __forceinline__ void tpose_tile(const float* __restrict__ W,
                                           f16* __restrict__ WT, int R, int C,
                                           int r0, int c0, f16 (*t)[72],
                                           int tid) {
#pragma unroll
  for (int p = 0; p < 2; ++p) {
    int lin = p * 2048 + tid * 4;
    int r = lin >> 6, c4 = lin & 63;
    fvec4 v = *(const fvec4*)(W + (size_t)(r0 + r) * C + c0 + c4);
    t[c4 + 0][r] = (f16)v[0];
    t[c4 + 1][r] = (f16)v[1];
    t[c4 + 2][r] = (f16)v[2];
    t[c4 + 3][r] = (f16)v[3];
  }
  __syncthreads();
#pragma unroll
  for (int p = 0; p < 2; ++p) {
    int lin = p * 2048 + tid * 4;
    int c = lin >> 6, r4 = lin & 63;
    f16x4 h;
    h[0] = t[c][r4 + 0];
    h[1] = t[c][r4 + 1];
    h[2] = t[c][r4 + 2];
    h[3] = t[c][r4 + 3];
    *(f16x4*)(WT + (size_t)(c0 + c) * R + r0 + r4) = h;
  }
  __syncthreads();
}

__device__ void run_role(const TDesc d, int rid, int nr, f16 (*t)[72],
                         int tid) {
  if (d.nMat <= 0 || d.W == nullptr) return;
  int tR = d.R >> 6, tC = d.C >> 6;
  int tpm = tR * tC, tot = tpm * d.nMat;
  for (int i = rid; i < tot; i += nr) {
    int m = i / tpm, rem = i - m * tpm;
    int r0 = (rem % tR) << 6, c0 = (rem / tR) << 6;
    tpose_tile(d.W + (size_t)m * d.sW, d.WT + (size_t)m * d.sWT, d.R, d.C, r0,
               c0, t, tid);
  }
}

// ---------------------------------------------------------------------------
// 8-wave intra-block split-K GEMM, 2-slot counted-vmcnt pipeline (64 KB LDS,
// 2 blocks/CU), k-quad XOR LDS swizzle (conflict-free fragment reads).
// C(M,N) = A(M,K) * BT(N,K)^T, 128x128 tile. Waves: quadrant q=wid&3 ->
// 64x64 output, half h=wid>>2 -> even/odd 32-wide K-subtiles; h=1 acc is
// reduced into h=0 via XOR-swizzled LDS after the loop.
// Per K-step: vmcnt(4) [next tile stays in flight, never drain] -> barrier ->
// ds_read slot kp&1 -> lgkmcnt(0) -> barrier -> stage kp+2 into freed slot ->
// 16 MFMA. Blocks >= nbGemm run transpose roles (z==0 only). Batched over
// grid.z via sBT/sBias/sOut strides.
// ---------------------------------------------------------------------------
#define GEMM8_ITER(KP, VM, DO_STAGE)                                          \
  {                                                                           \
    asm volatile("s_waitcnt vmcnt(" #VM ")" ::: "memory");                    \
    __builtin_amdgcn_s_barrier();                                             \
    const int slot_ = (KP) & 1;                                               \
    const f16* LA_ = base + slot_ * 16384 + h * 4096;                         \
    const f16* LB_ = base + slot_ * 16384 + 8192 + h * 4096;                  \
    f16x8 a_[4], b_[4];                                                       \
    _Pragma("unroll") for (int m_ = 0; m_ < 4; ++m_) a_[m_] =                 \
        *(const f16x8*)(LA_ +                                                 \
                        ((wr * 64 + m_ * 16 + lr) * 32 + (kg ^ xq) * 8));     \
    _Pragma("unroll") for (int n_ = 0; n_ < 4; ++n_) b_[n_] =                 \
        *(const f16x8*)(LB_ +                                                 \
                        ((wc * 64 + n_ * 16 + lr) * 32 + (kg ^ xq) * 8));     \
    asm volatile("s_waitcnt lgkmcnt(0)" ::: "memory");                        \
    __builtin_amdgcn_s_barrier();                                             \
    if (DO_STAGE) stageAB((KP) + 2, slot_);                                   \
    _Pragma("unroll") for (int m_ = 0; m_ < 4; ++m_)                          \
        _Pragma("unroll") for (int n_ = 0; n_ < 4; ++n_) acc[m_][n_] =        \
            __builtin_amdgcn_mfma_f32_16x16x32_f16(a_[m_], b_[n_],            \
                                                   acc[m_][n_], 0, 0, 0);     \
  }

template <int EP>
__global__ void __launch_bounds__(512)
gemm8(const f16* __restrict__ A, int lda, const f16* __restrict__ BT, int ldb,
      long long sBT, int K, int N, int gx, int nbGemm,
      const float* __restrict__ bias, long long sBias,
      const f16* __restrict__ addP, f16* __restrict__ outH,
      float* __restrict__ outF, long long sOut, const f16* __restrict__ zOld,
      const float* __restrict__ noise, float aT, float nsT, TDesc dA,
      TDesc dB) {
  __shared__ __align__(16) char smem[65536];
  const int tid = threadIdx.x;
  const int bid = blockIdx.x;

  if (bid >= nbGemm) {  // transpose-role block
    if (blockIdx.z == 0) {
      int rid = bid - nbGemm, nr = (int)gridDim.x - nbGemm;
      f16(*t)[72] = reinterpret_cast<f16(*)[72]>(smem);
      run_role(dA, rid, nr, t, tid);
      run_role(dB, rid, nr, t, tid);
    }
    return;
  }

  const int z = blockIdx.z;
  const f16* BTz = BT + (size_t)z * sBT;
  f16* outHz = outH ? outH + (size_t)z * sOut : nullptr;
  float* outFz = outF ? outF + (size_t)z * sOut : nullptr;

  // bijective XCD swizzle (nbGemm % 8 == 0)
  const int cpx = nbGemm >> 3;
  const int swz = (bid & 7) * cpx + (bid >> 3);
  const int by = swz / gx, bx = swz % gx;
  const int m0 = by * 128, n0 = bx * 128;

  const int lane = tid & 63, wid = tid >> 6;
  const int q = wid & 3, h = wid >> 2;
  const int wr = q >> 1, wc = q & 1;
  const int lr = lane & 15, kg = lane >> 4;
  const int xq = (lr >> 1) & 3;  // k-quad read swizzle (row bits 1-2 = lr 1-2)

  f16* base = (f16*)smem;  // 2 slots x 16384 f16 ([A_E][A_O][B_E][B_O] x 8KB)
  f32x4 acc[4][4] = {};

  const int nkp = K >> 6;  // K-pair steps of 64 (nkp >= 2)
  auto stageAB = [&](int kp, int slot) {
    int k0 = kp << 6;
    f16* s = base + slot * 16384;
    stage8s(A + (size_t)m0 * lda + k0, lda, s, tid);
    stage8s(A + (size_t)m0 * lda + k0 + 32, lda, s + 4096, tid);
    stage8s(BTz + (size_t)n0 * ldb + k0, ldb, s + 8192, tid);
    stage8s(BTz + (size_t)n0 * ldb + k0 + 32, ldb, s + 12288, tid);
  };

  stageAB(0, 0);
  stageAB(1, 1);
  int kp = 0;
  for (; kp < nkp - 1; ++kp) GEMM8_ITER(kp, 4, (kp + 2 < nkp));
  GEMM8_ITER(kp, 0, 0);

  // Cross-half reduce via LDS. Stride 128 with XOR row-swizzle
  // (row ^ ((col&7)<<2)): fits 64 KB exactly, 2-way banks (free).
  float* red = (float*)smem;
  if (h == 1) {
#pragma unroll
    for (int m = 0; m < 4; ++m)
#pragma unroll
      for (int n = 0; n < 4; ++n) {
        int row = wr * 64 + m * 16 + kg * 4;
        int col = wc * 64 + n * 16 + lr;
        int rs = row ^ ((col & 7) << 2);
        *(f32x4*)&red[(size_t)col * 128 + rs] = acc[m][n];
      }
  }
  __syncthreads();
  if (h != 0) return;

  float bcol[4];
  if constexpr (EP != EP_ADDP) {
    const float* biasz = bias + (size_t)z * sBias;
#pragma unroll
    for (int n = 0; n < 4; ++n) bcol[n] = biasz[n0 + wc * 64 + n * 16 + lr];
  }

#pragma unroll
  for (int m = 0; m < 4; ++m) {
    int rowb = m0 + wr * 64 + m * 16 + kg * 4;
    int rowl = wr * 64 + m * 16 + kg * 4;
#pragma unroll
    for (int n = 0; n < 4; ++n) {
      int col = n0 + wc * 64 + n * 16 + lr;
      int coll = wc * 64 + n * 16 + lr;
      int rsl = rowl ^ ((coll & 7) << 2);
      f32x4 osum = acc[m][n] + *(const f32x4*)&red[(size_t)coll * 128 + rsl];
#pragma unroll
      for (int r = 0; r < 4; ++r) {
        size_t idx = (size_t)(rowb + r) * N + col;
        float v = osum[r];
        if constexpr (EP == EP_ADDP) v += (float)addP[idx];
        else v += bcol[n];
        if constexpr (EP == EP_SILU || EP == EP_ADDP) {
          v = v / (1.0f + __expf(-v));
          outHz[idx] = (f16)v;
        } else if constexpr (EP == EP_LIN) {
          outHz[idx] = (f16)v;
        } else if constexpr (EP == EP_OUT) {
          outFz[idx] = v;
        } else {  // EP_ZUP: z' = a*(acc+b) + (1-a)*z_old + ns*noise (f16 chain)
          float zn = aT * v + (1.0f - aT) * (float)zOld[idx] + nsT * noise[idx];
          outHz[idx] = (f16)zn;
        }
      }
    }
  }
}

// ---------------------------------------------------------------------------
// 4-wave 128x128 GEMM (round-1 structure) — fallback path only.
// ---------------------------------------------------------------------------
template <int EP>
__global__ void __launch_bounds__(256)
gemm_bt(const f16* __restrict__ A0, const f16* __restrict__ A1, int Ksplit,
        int lda, const f16* __restrict__ BT, int ldb, long long sBT, int K,
        int N, int gx, const float* __restrict__ bias, long long sBias,
        f16* __restrict__ outH, float* __restrict__ outF, long long sOut,
        const float* __restrict__ zOld, const float* __restrict__ noise,
        float aT, float nsT) {
  __shared__ __align__(16) f16 lds[2][2][128 * 32];
  const int tid = threadIdx.x;
  const int z = blockIdx.z;
  const f16* BTz = BT + (size_t)z * sBT;
  f16* outHz = outH ? outH + (size_t)z * sOut : nullptr;
  float* outFz = outF ? outF + (size_t)z * sOut : nullptr;

  const int lane = tid & 63, wid = tid >> 6;
  const int wr = wid >> 1, wc = wid & 1;
  const int lr = lane & 15, kg = lane >> 4;
  const int by = blockIdx.x / gx, bx = blockIdx.x - by * gx;
  const int m0 = by * 128, n0 = bx * 128;

  f32x4 acc[4][4] = {};
  const int nk = K >> 5;
  auto stageAB = [&](int kt, int buf) {
    int k0 = kt << 5;
    const f16* Abase = (k0 < Ksplit)
                           ? (A0 + (size_t)m0 * lda + k0)
                           : (A1 + (size_t)m0 * lda + (k0 - Ksplit));
    stage_tile(Abase, lda, &lds[buf][0][0], tid, wid);
    stage_tile(BTz + (size_t)n0 * ldb + k0, ldb, &lds[buf][1][0], tid, wid);
  };

  stageAB(0, 0);
  __syncthreads();
  int cur = 0;
  for (int kt = 0; kt < nk; ++kt) {
    if (kt + 1 < nk) stageAB(kt + 1, cur ^ 1);
    const f16* LA = &lds[cur][0][0];
    const f16* LB = &lds[cur][1][0];
    f16x8 a[4], b[4];
#pragma unroll
    for (int m = 0; m < 4; ++m)
      a[m] = *(const f16x8*)(LA + ((wr * 64 + m * 16 + lr) * 32 + kg * 8));
#pragma unroll
    for (int n = 0; n < 4; ++n)
      b[n] = *(const f16x8*)(LB + ((wc * 64 + n * 16 + lr) * 32 + kg * 8));
#pragma unroll
    for (int m = 0; m < 4; ++m)
#pragma unroll
      for (int n = 0; n < 4; ++n)
        acc[m][n] = __builtin_amdgcn_mfma_f32_16x16x32_f16(a[m], b[n],
                                                           acc[m][n], 0, 0, 0);
    __syncthreads();
    cur ^= 1;
  }

  float bcol[4];
  const float* biasz = bias + (size_t)z * sBias;
#pragma unroll
  for (int n = 0; n < 4; ++n) bcol[n] = biasz[n0 + wc * 64 + n * 16 + lr];

#pragma unroll
  for (int m = 0; m < 4; ++m) {
    int rowb = m0 + wr * 64 + m * 16 + kg * 4;
#pragma unroll
    for (int n = 0; n < 4; ++n) {
      int col = n0 + wc * 64 + n * 16 + lr;
#pragma unroll
      for (int r = 0; r < 4; ++r) {
        size_t idx = (size_t)(rowb + r) * N + col;
        float v = acc[m][n][r] + bcol[n];
        if constexpr (EP == EP_SILU) {
          v = v / (1.0f + __expf(-v));
          outHz[idx] = (f16)v;
        } else if constexpr (EP == EP_LIN) {
          outHz[idx] = (f16)v;
        } else if constexpr (EP == EP_OUT) {
          outFz[idx] = v;
        } else {
          float zn = aT * v + (1.0f - aT) * zOld[idx] + nsT * noise[idx];
          outFz[idx] = zn;
          outHz[idx] = (f16)zn;
        }
      }
    }
  }
}

// ---------------------------------------------------------------------------
__global__ void __launch_bounds__(512) tconv_role(TDesc d) {
  __shared__ __align__(16) f16 t[64][72];
  run_role(d, blockIdx.x, gridDim.x, t, threadIdx.x);
}

__global__ void __launch_bounds__(256)
cvt4(const float* __restrict__ in, f16* __restrict__ outp, int n4) {
  int i = blockIdx.x * 256 + threadIdx.x;
  if (i >= n4) return;
  fvec4 v = *(const fvec4*)(in + (size_t)i * 4);
  f16x4 h;
  h[0] = (f16)v[0];
  h[1] = (f16)v[1];
  h[2] = (f16)v[2];
  h[3] = (f16)v[3];
  *(f16x4*)(outp + (size_t)i * 4) = h;
}

__global__ void __launch_bounds__(256)
zinit4(const float* __restrict__ z0, float* __restrict__ z32,
       f16* __restrict__ z16, int n4) {
  int i = blockIdx.x * 256 + threadIdx.x;
  if (i >= n4) return;
  fvec4 v = *(const fvec4*)(z0 + (size_t)i * 4);
  *(fvec4*)(z32 + (size_t)i * 4) = v;
  f16x4 h;
  h[0] = (f16)v[0];
  h[1] = (f16)v[1];
  h[2] = (f16)v[2];
  h[3] = (f16)v[3];
  *(f16x4*)(z16 + (size_t)i * 4) = h;
}

// ---------------------------------------------------------------------------
extern "C" void kernel_launch(void* const* d_in, const int* in_sizes, int n_in,
                              void* d_out, int out_size, void* d_ws,
                              size_t ws_size, hipStream_t stream) {
  const int B = 2048, IN = 1024, H = 2048, OUT = 1024, T = 10;
  const float* x = (const float*)d_in[0];
  const float* z0 = (const float*)d_in[1];
  const float* noise = (const float*)d_in[2];
  const float* w1 = (const float*)d_in[3];
  const float* b1 = (const float*)d_in[4];
  const float* w2 = (const float*)d_in[5];
  const float* b2 = (const float*)d_in[6];
  const float* wA = (const float*)d_in[7];
  const float* bA = (const float*)d_in[8];
  const float* wB = (const float*)d_in[9];
  const float* bB = (const float*)d_in[10];
  const float* wC = (const float*)d_in[11];
  const float* bC = (const float*)d_in[12];
  float* out = (float*)d_out;

  char* ws = (char*)d_ws;
  size_t off = 0;
  auto alloc = [&](size_t bytes) {
    void* p = ws + off;
    off += (bytes + 255) & ~(size_t)255;
    return p;
  };
  TDesc none = {nullptr, nullptr, 0, 0, 0, 0, 0};

  const size_t FAST_NEED = 273000000ull;
  if (ws_size >= FAST_NEED) {
    // ---------------- fast path ------------------------------------------
    f16* x16 = (f16*)alloc((size_t)B * IN * 2);
    f16* h16 = (f16*)alloc((size_t)B * H * 2);
    f16* xe16 = (f16*)alloc((size_t)B * H * 2);
    f16* z16 = (f16*)alloc((size_t)B * H * 2);
    f16* u16 = (f16*)alloc((size_t)B * H * 2);
    f16* p16 = (f16*)alloc((size_t)T * B * H * 2);
    f16* w1T = (f16*)alloc((size_t)IN * H * 2);
    f16* w2T = (f16*)alloc((size_t)H * H * 2);
    f16* wCT = (f16*)alloc((size_t)H * OUT * 2);
    f16* wAbotT = (f16*)alloc((size_t)T * H * H * 2);
    f16* wAtopT[2] = {(f16*)alloc((size_t)H * H * 2),
                      (f16*)alloc((size_t)H * H * 2)};
    f16* wBT2[2] = {(f16*)alloc((size_t)H * H * 2),
                    (f16*)alloc((size_t)H * H * 2)};

    cvt4<<<B * IN / 4 / 256, 256, 0, stream>>>(x, x16, B * IN / 4);
    cvt4<<<B * H / 4 / 256, 256, 0, stream>>>(z0, z16, B * H / 4);
    tconv_role<<<512, 512, 0, stream>>>(TDesc{w1, w1T, 0, 0, IN, H, 1});

    // embed1: h = silu(x @ w1 + b1); roles: w2T, wAbot 0..3
    gemm8<EP_SILU><<<512, 512, 0, stream>>>(
        x16, IN, w1T, IN, 0, IN, H, 16, 256, b1, 0, nullptr, h16, nullptr, 0,
        nullptr, nullptr, 0.f, 0.f, TDesc{w2, w2T, 0, 0, H, H, 1},
        TDesc{wA + (size_t)H * H, wAbotT, (long long)2 * H * H,
              (long long)H * H, H, H, 4});
    // embed2: xe = h @ w2 + b2; roles: wCT, wAbot 4..9
    gemm8<EP_LIN><<<512, 512, 0, stream>>>(
        h16, H, w2T, H, 0, H, H, 16, 256, b2, 0, nullptr, xe16, nullptr, 0,
        nullptr, nullptr, 0.f, 0.f, TDesc{wC, wCT, 0, 0, H, OUT, 1},
        TDesc{wA + (size_t)H * H + (size_t)4 * 2 * H * H,
              wAbotT + (size_t)4 * H * H, (long long)2 * H * H,
              (long long)H * H, H, H, 6});
    tconv_role<<<512, 512, 0, stream>>>(TDesc{wA, wAtopT[0], 0, 0, H, H, 1});

    // P_t = xe @ wAbot_t + bA_t, all t batched (grid.z = t)
    gemm8<EP_LIN><<<dim3(256, 1, T), 512, 0, stream>>>(
        xe16, H, wAbotT, H, (long long)H * H, H, H, 16, 256, bA, H, nullptr,
        p16, nullptr, (long long)B * H, nullptr, nullptr, 0.f, 0.f, none,
        none);

    for (int t = 0; t < T; ++t) {
      float alpha = (float)(0.99 - 0.01 * (double)t);
      float ns = sqrtf(1.0f - alpha);
      // u = silu(z @ wAtop_t + P_t); role: transpose wB_t
      gemm8<EP_ADDP><<<320, 512, 0, stream>>>(
          z16, H, wAtopT[t & 1], H, 0, H, H, 16, 256, nullptr, 0,
          p16 + (size_t)t * B * H, u16, nullptr, 0, nullptr, nullptr, 0.f,
          0.f, TDesc{wB + (size_t)t * H * H, wBT2[t & 1], 0, 0, H, H, 1},
          none);
      // z = a*(u @ wB_t + bB_t) + (1-a)z + ns*n_t; role: wAtop_{t+1}
      TDesc nextA = (t < T - 1)
                        ? TDesc{wA + (size_t)(t + 1) * 2 * H * H,
                                wAtopT[(t + 1) & 1], 0, 0, H, H, 1}
                        : none;
      gemm8<EP_ZUP><<<320, 512, 0, stream>>>(
          u16, H, wBT2[t & 1], H, 0, H, H, 16, 256, bB + (size_t)t * H, 0,
          nullptr, z16, nullptr, 0, z16, noise + (size_t)t * B * H, alpha, ns,
          nextA, none);
    }
    // out = z @ wC + bC
    gemm8<EP_OUT><<<128, 512, 0, stream>>>(
        z16, H, wCT, H, 0, H, OUT, 8, 128, bC, 0, nullptr, nullptr, out, 0,
        nullptr, nullptr, 0.f, 0.f, none, none);
  } else {
    // ---------------- fallback: round-1 flow ------------------------------
    f16* x16 = (f16*)alloc((size_t)B * IN * 2);
    f16* h16 = (f16*)alloc((size_t)B * H * 2);
    f16* xe16 = (f16*)alloc((size_t)B * H * 2);
    f16* z16 = (f16*)alloc((size_t)B * H * 2);
    f16* u16 = (f16*)alloc((size_t)B * H * 2);
    float* z32 = (float*)alloc((size_t)B * H * 4);
    f16* w1T = (f16*)alloc((size_t)IN * H * 2);
    f16* w2T = (f16*)alloc((size_t)H * H * 2);
    f16* wCT = (f16*)alloc((size_t)H * OUT * 2);
    f16* wAT = (f16*)alloc((size_t)2 * H * H * 2);
    f16* wBT = (f16*)alloc((size_t)H * H * 2);

    cvt4<<<B * IN / 4 / 256, 256, 0, stream>>>(x, x16, B * IN / 4);
    zinit4<<<B * H / 4 / 256, 256, 0, stream>>>(z0, z32, z16, B * H / 4);
    tconv_role<<<512, 512, 0, stream>>>(TDesc{w1, w1T, 0, 0, IN, H, 1});
    tconv_role<<<1024, 512, 0, stream>>>(TDesc{w2, w2T, 0, 0, H, H, 1});
    tconv_role<<<512, 512, 0, stream>>>(TDesc{wC, wCT, 0, 0, H, OUT, 1});

    gemm_bt<EP_SILU><<<dim3(256, 1, 1), 256, 0, stream>>>(
        x16, x16, IN, IN, w1T, IN, 0, IN, H, 16, b1, 0, h16, nullptr, 0,
        nullptr, nullptr, 0.f, 0.f);
    gemm_bt<EP_LIN><<<dim3(256, 1, 1), 256, 0, stream>>>(
        h16, h16, H, H, w2T, H, 0, H, H, 16, b2, 0, xe16, nullptr, 0, nullptr,
        nullptr, 0.f, 0.f);

    for (int t = 0; t < T; ++t) {
      float alpha = (float)(0.99 - 0.01 * (double)t);
      float ns = sqrtf(1.0f - alpha);
      tconv_role<<<1024, 512, 0, stream>>>(
          TDesc{wA + (size_t)t * 2 * H * H, wAT, 0, 0, 2 * H, H, 1});
      gemm_bt<EP_SILU><<<dim3(256, 1, 1), 256, 0, stream>>>(
          z16, xe16, H, H, wAT, 2 * H, 0, 2 * H, H, 16, bA + (size_t)t * H, 0,
          u16, nullptr, 0, nullptr, nullptr, 0.f, 0.f);
      tconv_role<<<1024, 512, 0, stream>>>(
          TDesc{wB + (size_t)t * H * H, wBT, 0, 0, H, H, 1});
      gemm_bt<EP_ZUP><<<dim3(256, 1, 1), 256, 0, stream>>>(
          u16, u16, H, H, wBT, H, 0, H, H, 16, bB + (size_t)t * H, 0, z16,
          z32, 0, z32, noise + (size_t)t * B * H, alpha, ns);
    }
    gemm_bt<EP_OUT><<<dim3(128, 1, 1), 256, 0, stream>>>(
        z16, z16, H, H, wCT, H, 0, H, OUT, 8, bC, 0, nullptr, out, 0, nullptr,
        nullptr, 0.f, 0.f);
  }
}